// Round 8
// baseline (2314.250 us; speedup 1.0000x reference)
//
#include <hip/hip_runtime.h>
#include <cstdint>

#define D_MODELC 256
#define N_LAYERSC 4
#define BATCHC 64
#define SEQC 900
#define NCH 10
#define CT 90
#define SUB 45
#define LN_EPSF 1e-5f
#define LOG2E 1.44269504088896f

typedef __bf16 bf16x8 __attribute__((ext_vector_type(8)));
typedef __bf16 bf16x4 __attribute__((ext_vector_type(4)));
typedef float floatx4 __attribute__((ext_vector_type(4)));

#if defined(__has_builtin)
#if __has_builtin(__builtin_amdgcn_exp2f)
#define EXP2F __builtin_amdgcn_exp2f
#endif
#endif
#ifndef EXP2F
#define EXP2F exp2f
#endif

__device__ inline float sp(float v) { return (v > 20.f) ? v : log1pf(__expf(v)); }
__device__ inline float silu(float v) { return v / (1.f + __expf(-v)); }

// ---------------- weight transpose + cvt: W (L,K,N) -> Wb (L,N,K) bf16
__global__ void wprep(const float* __restrict__ W, __bf16* __restrict__ Wb,
                      int K, int N, int kshift) {
  int l = blockIdx.y;
  int idx = blockIdx.x * 256 + threadIdx.x;
  if (idx >= N * K) return;
  int n = idx >> kshift, k = idx & (K - 1);
  Wb[(size_t)l * N * K + idx] = (__bf16)W[(size_t)l * K * N + (size_t)k * N + n];
}

// ---------------- embed -> split bf16 x
__global__ void embed_kernel(const int* __restrict__ grid,
                             const float* __restrict__ cemb,
                             const float* __restrict__ pemb,
                             __bf16* __restrict__ xh, __bf16* __restrict__ xl) {
  int row = blockIdx.x;
  int c = threadIdx.x;
  int s = row % SEQC;
  int g = grid[row];
  float v = cemb[g * D_MODELC + c] + pemb[s * D_MODELC + c];
  size_t o = (size_t)row * D_MODELC + c;
  __bf16 hh = (__bf16)v;
  xh[o] = hh;
  xl[o] = (__bf16)(v - (float)hh);
}

// ---------------- bf16 MFMA GEMM: C = A(MxK) * W^T(NxK) + bias
// 128x128 tile, 4 waves (2x2), BK=32. M % 128 == 0, K % 32 == 0.
// Grid: x = COLUMN tiles (fast-varying, for A L2-reuse), y = row tiles.
// mode 0: fp32 out Cf
// mode 1: bf16 out Cb, softplus applied to cols < 16 (x-proj: delta pre-act)
// mode 2: in-proj: col<512 -> Cb = v ; col>=512 -> Cg = silu(v)
#define GLDA 40   // 80 B row stride: 16B-aligned, <=2-way bank aliasing (free)
__global__ __launch_bounds__(256) void gemm_bf16(
    const __bf16* __restrict__ A, const __bf16* __restrict__ W,
    const float* __restrict__ bias,
    float* __restrict__ Cf, __bf16* __restrict__ Cb, __bf16* __restrict__ Cg,
    int M, int N, int K, int mode) {
  __shared__ __attribute__((aligned(16))) __bf16 As[128 * GLDA];
  __shared__ __attribute__((aligned(16))) __bf16 Bs[128 * GLDA];
  int tid = threadIdx.x, lane = tid & 63, w = tid >> 6;
  int bm = blockIdx.y * 128, bn = blockIdx.x * 128;
  int wm = (w >> 1) * 64, wn = (w & 1) * 64;
  int lm = lane & 15, kq = lane >> 4;

  floatx4 acc[4][4];
  floatx4 zero = {0.f, 0.f, 0.f, 0.f};
  #pragma unroll
  for (int i = 0; i < 4; ++i)
    #pragma unroll
    for (int j = 0; j < 4; ++j) acc[i][j] = zero;

  int r0 = tid >> 1;          // 0..127
  int kb = (tid & 1) * 16;    // 0 / 16

  for (int k0 = 0; k0 < K; k0 += 32) {
    __syncthreads();
    {
      size_t aoff = (size_t)(bm + r0) * K + k0 + kb;
      *(bf16x8*)&As[r0 * GLDA + kb]     = *(const bf16x8*)&A[aoff];
      *(bf16x8*)&As[r0 * GLDA + kb + 8] = *(const bf16x8*)&A[aoff + 8];
      int nr = bn + r0;
      if (nr < N) {
        size_t boff = (size_t)nr * K + k0 + kb;
        *(bf16x8*)&Bs[r0 * GLDA + kb]     = *(const bf16x8*)&W[boff];
        *(bf16x8*)&Bs[r0 * GLDA + kb + 8] = *(const bf16x8*)&W[boff + 8];
      } else {
        uint4 zu = make_uint4(0, 0, 0, 0);
        *(uint4*)&Bs[r0 * GLDA + kb] = zu;
        *(uint4*)&Bs[r0 * GLDA + kb + 8] = zu;
      }
    }
    __syncthreads();
    bf16x8 fa[4], fb[4];
    #pragma unroll
    for (int mt = 0; mt < 4; ++mt)
      fa[mt] = *(const bf16x8*)&As[(wm + mt * 16 + lm) * GLDA + kq * 8];
    #pragma unroll
    for (int nt = 0; nt < 4; ++nt)
      fb[nt] = *(const bf16x8*)&Bs[(wn + nt * 16 + lm) * GLDA + kq * 8];
    #pragma unroll
    for (int mt = 0; mt < 4; ++mt)
      #pragma unroll
      for (int nt = 0; nt < 4; ++nt)
        acc[mt][nt] = __builtin_amdgcn_mfma_f32_16x16x32_bf16(fa[mt], fb[nt], acc[mt][nt], 0, 0, 0);
  }
  #pragma unroll
  for (int mt = 0; mt < 4; ++mt)
    #pragma unroll
    for (int nt = 0; nt < 4; ++nt) {
      int col = bn + wn + nt * 16 + lm;
      if (col >= N) continue;
      float bz = bias[col];
      #pragma unroll
      for (int i = 0; i < 4; ++i) {
        int row = bm + wm + mt * 16 + kq * 4 + i;
        float v = acc[mt][nt][i] + bz;
        if (mode == 0) {
          Cf[(size_t)row * N + col] = v;
        } else if (mode == 1) {
          if (col < 16) v = sp(v);           // softplus(delta) once here
          Cb[(size_t)row * N + col] = (__bf16)v;
        } else {
          if (col < 512) Cb[(size_t)row * 512 + col] = (__bf16)v;
          else           Cg[(size_t)row * 512 + col - 512] = (__bf16)silu(v);
        }
      }
    }
}

// ---------------- depthwise causal conv (k=4) + SiLU, bf16 in/out, 8 ch/thread
__global__ void conv_silu(const __bf16* __restrict__ xs,
                          const float* __restrict__ cw,
                          const float* __restrict__ cb,
                          __bf16* __restrict__ xc, int total) {
  int idx = blockIdx.x * 256 + threadIdx.x;   // < R*64
  if (idx >= total) return;
  int d8 = (idx & 63) * 8;
  int bt = idx >> 6;
  int t = bt % SEQC;
  const __bf16* base = xs + (size_t)(bt - t) * 512 + d8;
  float wv[8][4];
  #pragma unroll
  for (int e = 0; e < 8; ++e) {
    float4 wq = *(const float4*)&cw[(d8 + e) * 4];
    wv[e][0] = wq.x; wv[e][1] = wq.y; wv[e][2] = wq.z; wv[e][3] = wq.w;
  }
  float4 b0 = *(const float4*)&cb[d8];
  float4 b1 = *(const float4*)&cb[d8 + 4];
  float acc[8] = {b0.x, b0.y, b0.z, b0.w, b1.x, b1.y, b1.z, b1.w};
  #pragma unroll
  for (int j = 0; j < 4; ++j) {
    int ts = t - 3 + j;
    if (ts >= 0) {
      bf16x8 v = *(const bf16x8*)&base[(size_t)ts * 512];
      #pragma unroll
      for (int e = 0; e < 8; ++e) acc[e] = fmaf(wv[e][j], (float)v[e], acc[e]);
    }
  }
  bf16x8 o;
  #pragma unroll
  for (int e = 0; e < 8; ++e) o[e] = (__bf16)silu(acc[e]);
  *(bf16x8*)&xc[(size_t)bt * 512 + d8] = o;
}

// ---------------- scan phase 1: per-chunk local scan (h=0) -> hend, P (bf16)
// 256 threads = 4 d-groups; (delta|B) tile staged once for all 4 groups.
__global__ __launch_bounds__(256, 4) void scan_phase1(
    const __bf16* __restrict__ ssm, const float* __restrict__ A_log,
    const __bf16* __restrict__ xc,
    __bf16* __restrict__ hend, __bf16* __restrict__ Pp) {
  __shared__ float sb[SUB * 32];
  __shared__ __bf16 xsb[SUB * 256];
  int b = blockIdx.x, half = blockIdx.y, c = blockIdx.z;
  int tid = threadIdx.x;
  int dg0 = half * 256;
  int d = dg0 + tid;
  float a2[16];
  #pragma unroll
  for (int n = 0; n < 16; ++n) a2[n] = -__expf(A_log[d * 16 + n]) * LOG2E;
  float h[16] = {}, S[16] = {};
  size_t rowbase = (size_t)b * SEQC + c * CT;

  for (int sub = 0; sub < 2; ++sub) {
    int ts0 = sub * SUB;
    __syncthreads();
    for (int i = tid; i < SUB * 8; i += 256) {
      int tt = i >> 3, n4 = (i & 7) * 4;
      bf16x4 v = *(const bf16x4*)&ssm[(rowbase + ts0 + tt) * 32 + n4];
      float4 f = {(float)v[0], (float)v[1], (float)v[2], (float)v[3]};
      *(float4*)&sb[tt * 32 + n4] = f;
    }
    for (int i = tid; i < SUB * 64; i += 256) {
      int tt = i >> 6, j4 = (i & 63) * 4;
      *(bf16x4*)&xsb[tt * 256 + j4] =
          *(const bf16x4*)&xc[(rowbase + ts0 + tt) * 512 + dg0 + j4];
    }
    __syncthreads();
    for (int tt = 0; tt < SUB; ++tt) {
      const float4* dv = (const float4*)&sb[tt * 32];
      float4 d0 = dv[0], d1 = dv[1], d2 = dv[2], d3 = dv[3];
      float4 e0 = dv[4], e1 = dv[5], e2 = dv[6], e3 = dv[7];
      float del[16] = {d0.x, d0.y, d0.z, d0.w, d1.x, d1.y, d1.z, d1.w,
                       d2.x, d2.y, d2.z, d2.w, d3.x, d3.y, d3.z, d3.w};
      float Bv[16]  = {e0.x, e0.y, e0.z, e0.w, e1.x, e1.y, e1.z, e1.w,
                       e2.x, e2.y, e2.z, e2.w, e3.x, e3.y, e3.z, e3.w};
      float xv = (float)xsb[tt * 256 + tid];
      #pragma unroll
      for (int n = 0; n < 16; ++n) {
        S[n] += del[n];
        float e = EXP2F(a2[n] * del[n]);
        h[n] = fmaf(h[n], e, xv * Bv[n]);
      }
    }
  }
  size_t base = ((size_t)(b * NCH + c) * 512 + d) * 16;
  bf16x8 h0, h1, p0, p1;
  #pragma unroll
  for (int n = 0; n < 8; ++n) {
    h0[n] = (__bf16)h[n]; h1[n] = (__bf16)h[n + 8];
    p0[n] = (__bf16)EXP2F(a2[n] * S[n]);
    p1[n] = (__bf16)EXP2F(a2[n + 8] * S[n + 8]);
  }
  *(bf16x8*)&hend[base] = h0; *(bf16x8*)&hend[base + 8] = h1;
  *(bf16x8*)&Pp[base] = p0;   *(bf16x8*)&Pp[base + 8] = p1;
}

// ---------------- scan phase 2: sequential carry composition (hend -> hin in place)
__global__ __launch_bounds__(64) void scan_combine(
    __bf16* __restrict__ hend, const __bf16* __restrict__ Pp) {
  int b = blockIdx.x;
  int d = blockIdx.y * 64 + threadIdx.x;
  float hp[16] = {};
  for (int c = 0; c < NCH; ++c) {
    size_t base = ((size_t)(b * NCH + c) * 512 + d) * 16;
    bf16x8 he0 = *(const bf16x8*)&hend[base];
    bf16x8 he1 = *(const bf16x8*)&hend[base + 8];
    bf16x8 pp0 = *(const bf16x8*)&Pp[base];
    bf16x8 pp1 = *(const bf16x8*)&Pp[base + 8];
    bf16x8 o0, o1;
    #pragma unroll
    for (int n = 0; n < 8; ++n) {
      o0[n] = (__bf16)hp[n]; o1[n] = (__bf16)hp[n + 8];
      hp[n]     = fmaf((float)pp0[n], hp[n],     (float)he0[n]);
      hp[n + 8] = fmaf((float)pp1[n], hp[n + 8], (float)he1[n]);
    }
    *(bf16x8*)&hend[base] = o0; *(bf16x8*)&hend[base + 8] = o1;
  }
}

// ---------------- scan phase 3: local scan with carry, y, gate -> yc bf16
// 256 threads = 4 d-groups sharing the (delta|B) stage.
__global__ __launch_bounds__(256, 4) void scan_phase3(
    const __bf16* __restrict__ ssm, const float* __restrict__ A_log,
    const float* __restrict__ Dp, const __bf16* __restrict__ xc,
    const __bf16* __restrict__ gate, const __bf16* __restrict__ hin,
    __bf16* __restrict__ yc) {
  __shared__ float sb[SUB * 32];
  __shared__ __bf16 xsb[SUB * 256];
  int b = blockIdx.x, half = blockIdx.y, c = blockIdx.z;
  int tid = threadIdx.x;
  int dg0 = half * 256;
  int d = dg0 + tid;
  float a2[16];
  #pragma unroll
  for (int n = 0; n < 16; ++n) a2[n] = -__expf(A_log[d * 16 + n]) * LOG2E;
  float Dv = Dp[d];
  float h[16];
  {
    size_t base = ((size_t)(b * NCH + c) * 512 + d) * 16;
    bf16x8 h0 = *(const bf16x8*)&hin[base];
    bf16x8 h1 = *(const bf16x8*)&hin[base + 8];
    #pragma unroll
    for (int n = 0; n < 8; ++n) { h[n] = (float)h0[n]; h[n + 8] = (float)h1[n]; }
  }
  size_t rowbase = (size_t)b * SEQC + c * CT;

  for (int sub = 0; sub < 2; ++sub) {
    int ts0 = sub * SUB;
    __syncthreads();
    for (int i = tid; i < SUB * 8; i += 256) {
      int tt = i >> 3, n4 = (i & 7) * 4;
      bf16x4 v = *(const bf16x4*)&ssm[(rowbase + ts0 + tt) * 32 + n4];
      float4 f = {(float)v[0], (float)v[1], (float)v[2], (float)v[3]};
      *(float4*)&sb[tt * 32 + n4] = f;
    }
    for (int i = tid; i < SUB * 64; i += 256) {
      int tt = i >> 6, j4 = (i & 63) * 4;
      *(bf16x4*)&xsb[tt * 256 + j4] =
          *(const bf16x4*)&xc[(rowbase + ts0 + tt) * 512 + dg0 + j4];
    }
    __syncthreads();
    for (int tt = 0; tt < SUB; ++tt) {
      const float4* dv = (const float4*)&sb[tt * 32];
      float4 d0 = dv[0], d1 = dv[1], d2 = dv[2], d3 = dv[3];
      float4 e0 = dv[4], e1 = dv[5], e2 = dv[6], e3 = dv[7];
      float del[16] = {d0.x, d0.y, d0.z, d0.w, d1.x, d1.y, d1.z, d1.w,
                       d2.x, d2.y, d2.z, d2.w, d3.x, d3.y, d3.z, d3.w};
      float Bv[16]  = {e0.x, e0.y, e0.z, e0.w, e1.x, e1.y, e1.z, e1.w,
                       e2.x, e2.y, e2.z, e2.w, e3.x, e3.y, e3.z, e3.w};
      float xv = (float)xsb[tt * 256 + tid];
      float y0 = 0.f, y1 = 0.f, y2 = 0.f, y3 = 0.f;
      #pragma unroll
      for (int n = 0; n < 4; ++n) {
        float e = EXP2F(a2[n] * del[n]);
        h[n] = fmaf(h[n], e, xv * Bv[n]);
        y0 = fmaf(h[n], Bv[n], y0);
      }
      #pragma unroll
      for (int n = 4; n < 8; ++n) {
        float e = EXP2F(a2[n] * del[n]);
        h[n] = fmaf(h[n], e, xv * Bv[n]);
        y1 = fmaf(h[n], Bv[n], y1);
      }
      #pragma unroll
      for (int n = 8; n < 12; ++n) {
        float e = EXP2F(a2[n] * del[n]);
        h[n] = fmaf(h[n], e, xv * Bv[n]);
        y2 = fmaf(h[n], Bv[n], y2);
      }
      #pragma unroll
      for (int n = 12; n < 16; ++n) {
        float e = EXP2F(a2[n] * del[n]);
        h[n] = fmaf(h[n], e, xv * Bv[n]);
        y3 = fmaf(h[n], Bv[n], y3);
      }
      xsb[tt * 256 + tid] = (__bf16)fmaf(Dv, xv, (y0 + y1) + (y2 + y3));
    }
    __syncthreads();
    for (int i = tid; i < SUB * 64; i += 256) {
      int tt = i >> 6, j4 = (i & 63) * 4;
      size_t o = (rowbase + ts0 + tt) * 512 + dg0 + j4;
      bf16x4 y4 = *(const bf16x4*)&xsb[tt * 256 + j4];
      bf16x4 g4 = *(const bf16x4*)&gate[o];
      bf16x4 r;
      #pragma unroll
      for (int e = 0; e < 4; ++e) r[e] = (__bf16)((float)y4[e] * (float)g4[e]);
      *(bf16x4*)&yc[o] = r;
    }
  }
}

// ---------------- x = LayerNorm(reconstruct(xh,xl) + ob), re-split; 4 rows/block
__global__ __launch_bounds__(256) void add_ln(
    __bf16* __restrict__ xh, __bf16* __restrict__ xl,
    const float* __restrict__ ob,
    const float* __restrict__ g, const float* __restrict__ bb) {
  int lane = threadIdx.x & 63;
  size_t base = ((size_t)blockIdx.x * 4 + (threadIdx.x >> 6)) * 256;
  bf16x4 h4 = *(const bf16x4*)&xh[base + lane * 4];
  bf16x4 l4 = *(const bf16x4*)&xl[base + lane * 4];
  float4 o4 = *(const float4*)&ob[base + lane * 4];
  float ov[4] = {o4.x, o4.y, o4.z, o4.w};
  float v[4];
  #pragma unroll
  for (int i = 0; i < 4; ++i) v[i] = (float)h4[i] + (float)l4[i] + ov[i];
  float s = v[0] + v[1] + v[2] + v[3];
  #pragma unroll
  for (int off = 32; off > 0; off >>= 1) s += __shfl_down(s, off);
  float mu = __shfl(s, 0) * (1.f / 256.f);
  float var = 0.f;
  #pragma unroll
  for (int i = 0; i < 4; ++i) { float dd = v[i] - mu; var = fmaf(dd, dd, var); }
  #pragma unroll
  for (int off = 32; off > 0; off >>= 1) var += __shfl_down(var, off);
  float r = rsqrtf(__shfl(var, 0) * (1.f / 256.f) + LN_EPSF);
  float4 gv = *(const float4*)&g[lane * 4];
  float4 bv = *(const float4*)&bb[lane * 4];
  float gg[4] = {gv.x, gv.y, gv.z, gv.w};
  float bbv[4] = {bv.x, bv.y, bv.z, bv.w};
  bf16x4 hq, lq;
  #pragma unroll
  for (int i = 0; i < 4; ++i) {
    float o = (v[i] - mu) * r * gg[i] + bbv[i];
    __bf16 hh = (__bf16)o;
    hq[i] = hh;
    lq[i] = (__bf16)(o - (float)hh);
  }
  *(bf16x4*)&xh[base + lane * 4] = hq;
  *(bf16x4*)&xl[base + lane * 4] = lq;
}

// ---------------- fin[b][256] = reconstruct(x) at t=899
__global__ void extract_final(const __bf16* __restrict__ xh,
                              const __bf16* __restrict__ xl,
                              float* __restrict__ fin) {
  int b = blockIdx.x;
  int c = threadIdx.x;
  size_t o = ((size_t)b * SEQC + (SEQC - 1)) * D_MODELC + c;
  fin[(size_t)b * 256 + c] = (float)xh[o] + (float)xl[o];
}

// ---------------- final heads
__global__ __launch_bounds__(128) void heads_kernel(
    const float* __restrict__ fin,
    const float* __restrict__ cnt1_w, const float* __restrict__ cnt1_b,
    const float* __restrict__ cnt2_w, const float* __restrict__ cnt2_b,
    const float* __restrict__ col1_w, const float* __restrict__ col1_b,
    const float* __restrict__ col2_w, const float* __restrict__ col2_b,
    float* __restrict__ out) {
  int b = blockIdx.x;
  int tid = threadIdx.x;
  __shared__ float f[256];
  __shared__ float hc[128];
  __shared__ float hl[128];
  f[tid] = fin[b * 256 + tid];
  f[tid + 128] = fin[b * 256 + tid + 128];
  __syncthreads();
  float s1 = cnt1_b[tid], s2 = col1_b[tid];
  for (int c = 0; c < 256; ++c) {
    float v = f[c];
    s1 = fmaf(v, cnt1_w[c * 128 + tid], s1);
    s2 = fmaf(v, col1_w[c * 128 + tid], s2);
  }
  hc[tid] = fmaxf(s1, 0.f);
  hl[tid] = fmaxf(s2, 0.f);
  __syncthreads();
  if (tid == 0) {
    float t = cnt2_b[0];
    for (int j = 0; j < 128; ++j) t = fmaf(hc[j], cnt2_w[j], t);
    out[b] = fmaxf(t, 0.f);
  }
  if (tid < 10) {
    float t = col2_b[tid];
    for (int j = 0; j < 128; ++j) t = fmaf(hl[j], col2_w[j * 10 + tid], t);
    out[64 + b * 10 + tid] = fmaxf(t, 0.f);
  }
}

extern "C" void kernel_launch(void* const* d_in, const int* in_sizes, int n_in,
                              void* d_out, int out_size, void* d_ws, size_t ws_size,
                              hipStream_t stream) {
  const int*   grid   = (const int*)d_in[0];
  const float* cemb   = (const float*)d_in[1];
  const float* pemb   = (const float*)d_in[2];
  const float* in_w   = (const float*)d_in[3];
  const float* in_b   = (const float*)d_in[4];
  const float* conv_w = (const float*)d_in[5];
  const float* conv_b = (const float*)d_in[6];
  const float* xproj_w= (const float*)d_in[7];
  const float* xproj_b= (const float*)d_in[8];
  const float* A_log  = (const float*)d_in[9];
  const float* Dp     = (const float*)d_in[10];
  const float* out_w  = (const float*)d_in[11];
  const float* out_b  = (const float*)d_in[12];
  const float* ln_g   = (const float*)d_in[13];
  const float* ln_b   = (const float*)d_in[14];
  const float* cnt1_w = (const float*)d_in[15];
  const float* cnt1_b = (const float*)d_in[16];
  const float* cnt2_w = (const float*)d_in[17];
  const float* cnt2_b = (const float*)d_in[18];
  const float* col1_w = (const float*)d_in[19];
  const float* col1_b = (const float*)d_in[20];
  const float* col2_w = (const float*)d_in[21];
  const float* col2_b = (const float*)d_in[22];

  const int R = BATCHC * SEQC;  // 57600
  float* ws = (float*)d_ws;
  size_t off = 0;
  auto alloc = [&](size_t fl) { float* p = ws + off; off += (fl + 63) & ~(size_t)63; return p; };

  float*  fin   = alloc((size_t)BATCHC * 256);
  __bf16* wi    = (__bf16*)alloc((size_t)N_LAYERSC * 1024 * 256 / 2);
  __bf16* wx    = (__bf16*)alloc((size_t)N_LAYERSC * 32 * 512 / 2);
  __bf16* wo    = (__bf16*)alloc((size_t)N_LAYERSC * 256 * 512 / 2);
  __bf16* xh    = (__bf16*)alloc((size_t)R * 256 / 2);
  __bf16* xl    = (__bf16*)alloc((size_t)R * 256 / 2);
  __bf16* xsyc  = (__bf16*)alloc((size_t)R * 512 / 2);   // xs then yc
  float*  gateob= alloc((size_t)R * 512 / 2);            // gate bf16, then ob fp32
  __bf16* xc    = (__bf16*)alloc((size_t)R * 512 / 2);
  __bf16* ssm   = (__bf16*)alloc((size_t)R * 32 / 2);
  __bf16* hend  = (__bf16*)alloc((size_t)BATCHC * NCH * 512 * 16 / 2);
  __bf16* Pp    = (__bf16*)alloc((size_t)BATCHC * NCH * 512 * 16 / 2);
  __bf16* gate  = (__bf16*)gateob;
  float*  ob    = gateob;

  // weight prep (once per call)
  wprep<<<dim3(1024, N_LAYERSC), 256, 0, stream>>>(in_w, wi, 256, 1024, 8);
  wprep<<<dim3(64, N_LAYERSC), 256, 0, stream>>>(xproj_w, wx, 512, 32, 9);
  wprep<<<dim3(512, N_LAYERSC), 256, 0, stream>>>(out_w, wo, 512, 256, 9);

  embed_kernel<<<R, 256, 0, stream>>>(grid, cemb, pemb, xh, xl);

  for (int l = 0; l < N_LAYERSC; ++l) {
    // in-proj: xs (bf16) + gate = silu(res) (bf16). grid: x=col tiles (8)
    gemm_bf16<<<dim3(8, R / 128), 256, 0, stream>>>(
        xh, wi + (size_t)l * 1024 * 256, in_b + l * 1024,
        nullptr, xsyc, gate, R, 1024, 256, 2);
    conv_silu<<<(R * 64 + 255) / 256, 256, 0, stream>>>(
        xsyc, conv_w + (size_t)l * 512 * 4, conv_b + l * 512, xc, R * 64);
    // x-proj: ssm bf16, softplus fused on delta cols
    gemm_bf16<<<dim3(1, R / 128), 256, 0, stream>>>(
        xc, wx + (size_t)l * 32 * 512, xproj_b + l * 32,
        nullptr, ssm, nullptr, R, 32, 512, 1);
    scan_phase1<<<dim3(BATCHC, 2, NCH), 256, 0, stream>>>(
        ssm, A_log + (size_t)l * 512 * 16, xc, hend, Pp);
    scan_combine<<<dim3(BATCHC, 8), 64, 0, stream>>>(hend, Pp);
    scan_phase3<<<dim3(BATCHC, 2, NCH), 256, 0, stream>>>(
        ssm, A_log + (size_t)l * 512 * 16, Dp + l * 512, xc, gate, hend, xsyc);
    // out-proj: ob fp32. grid: x=col tiles (2)
    gemm_bf16<<<dim3(2, R / 128), 256, 0, stream>>>(
        xsyc, wo + (size_t)l * 256 * 512, out_b + l * 256,
        ob, nullptr, nullptr, R, 256, 512, 0);
    add_ln<<<R / 4, 256, 0, stream>>>(xh, xl, ob, ln_g, ln_b);
  }

  extract_final<<<BATCHC, 256, 0, stream>>>(xh, xl, fin);
  heads_kernel<<<BATCHC, 128, 0, stream>>>(
      fin, cnt1_w, cnt1_b, cnt2_w, cnt2_b, col1_w, col1_b, col2_w, col2_b,
      (float*)d_out);
}

// Round 9
// 2232.380 us; speedup vs baseline: 1.0367x; 1.0367x over previous
//
#include <hip/hip_runtime.h>
#include <cstdint>

#define D_MODELC 256
#define N_LAYERSC 4
#define BATCHC 64
#define SEQC 900
#define NCH 10
#define CT 90
#define SUB 45
#define LN_EPSF 1e-5f
#define LOG2E 1.44269504088896f

typedef __bf16 bf16x8 __attribute__((ext_vector_type(8)));
typedef __bf16 bf16x4 __attribute__((ext_vector_type(4)));
typedef float floatx4 __attribute__((ext_vector_type(4)));

#if defined(__has_builtin)
#if __has_builtin(__builtin_amdgcn_exp2f)
#define EXP2F __builtin_amdgcn_exp2f
#endif
#endif
#ifndef EXP2F
#define EXP2F exp2f
#endif

__device__ inline float sp(float v) { return (v > 20.f) ? v : log1pf(__expf(v)); }
__device__ inline float silu(float v) { return v / (1.f + __expf(-v)); }

// ---------------- weight transpose + cvt: W (L,K,N) -> Wb (L,N,K) bf16
__global__ void wprep(const float* __restrict__ W, __bf16* __restrict__ Wb,
                      int K, int N, int kshift) {
  int l = blockIdx.y;
  int idx = blockIdx.x * 256 + threadIdx.x;
  if (idx >= N * K) return;
  int n = idx >> kshift, k = idx & (K - 1);
  Wb[(size_t)l * N * K + idx] = (__bf16)W[(size_t)l * K * N + (size_t)k * N + n];
}

// ---------------- embed -> split bf16 x
__global__ void embed_kernel(const int* __restrict__ grid,
                             const float* __restrict__ cemb,
                             const float* __restrict__ pemb,
                             __bf16* __restrict__ xh, __bf16* __restrict__ xl) {
  int row = blockIdx.x;
  int c = threadIdx.x;
  int s = row % SEQC;
  int g = grid[row];
  float v = cemb[g * D_MODELC + c] + pemb[s * D_MODELC + c];
  size_t o = (size_t)row * D_MODELC + c;
  __bf16 hh = (__bf16)v;
  xh[o] = hh;
  xl[o] = (__bf16)(v - (float)hh);
}

// ---------------- bf16 MFMA GEMM: C = A(MxK) * W^T(NxK) + bias
// 128x128 tile, 4 waves (2x2), BK=32, software-pipelined:
// LDS double-buffer + register prefetch 2 iters ahead, 1 barrier/iter.
// M % 128 == 0, K % 32 == 0.
// mode 0: fp32 out Cf
// mode 1: bf16 out Cb, softplus applied to cols < 16 (x-proj delta)
// mode 2: in-proj: col<512 -> Cb = v ; col>=512 -> Cg = silu(v)
#define GLDA 40   // 80 B row stride: 16B-aligned
__global__ __launch_bounds__(256) void gemm_bf16(
    const __bf16* __restrict__ A, const __bf16* __restrict__ W,
    const float* __restrict__ bias,
    float* __restrict__ Cf, __bf16* __restrict__ Cb, __bf16* __restrict__ Cg,
    int M, int N, int K, int mode) {
  __shared__ __attribute__((aligned(16))) __bf16 As[2][128 * GLDA];
  __shared__ __attribute__((aligned(16))) __bf16 Bs[2][128 * GLDA];
  int tid = threadIdx.x, lane = tid & 63, w = tid >> 6;
  int bm = blockIdx.y * 128, bn = blockIdx.x * 128;
  int wm = (w >> 1) * 64, wn = (w & 1) * 64;
  int lm = lane & 15, kq = lane >> 4;

  floatx4 acc[4][4];
  floatx4 zero = {0.f, 0.f, 0.f, 0.f};
  #pragma unroll
  for (int i = 0; i < 4; ++i)
    #pragma unroll
    for (int j = 0; j < 4; ++j) acc[i][j] = zero;

  int r0 = tid >> 1;          // 0..127
  int kb = (tid & 1) * 16;    // 0 / 16
  int nr = bn + r0;
  bool bok = (nr < N);

  bf16x8 ra0, ra1, rb0, rb1;
  auto gload = [&](int k0) {
    size_t aoff = (size_t)(bm + r0) * K + k0 + kb;
    ra0 = *(const bf16x8*)&A[aoff];
    ra1 = *(const bf16x8*)&A[aoff + 8];
    if (bok) {
      size_t boff = (size_t)nr * K + k0 + kb;
      rb0 = *(const bf16x8*)&W[boff];
      rb1 = *(const bf16x8*)&W[boff + 8];
    } else {
      #pragma unroll
      for (int e = 0; e < 8; ++e) { rb0[e] = (__bf16)0.f; rb1[e] = (__bf16)0.f; }
    }
  };
  auto lstore = [&](int buf) {
    *(bf16x8*)&As[buf][r0 * GLDA + kb]     = ra0;
    *(bf16x8*)&As[buf][r0 * GLDA + kb + 8] = ra1;
    *(bf16x8*)&Bs[buf][r0 * GLDA + kb]     = rb0;
    *(bf16x8*)&Bs[buf][r0 * GLDA + kb + 8] = rb1;
  };

  int nk = K >> 5;
  gload(0);
  lstore(0);
  gload(32);                 // prefetch k=1 (nk >= 8 always here)
  __syncthreads();

  for (int k = 0; k < nk; ++k) {
    int cur = k & 1;
    bf16x8 fa[4], fb[4];
    #pragma unroll
    for (int mt = 0; mt < 4; ++mt)
      fa[mt] = *(const bf16x8*)&As[cur][(wm + mt * 16 + lm) * GLDA + kq * 8];
    #pragma unroll
    for (int nt = 0; nt < 4; ++nt)
      fb[nt] = *(const bf16x8*)&Bs[cur][(wn + nt * 16 + lm) * GLDA + kq * 8];
    #pragma unroll
    for (int mt = 0; mt < 4; ++mt)
      #pragma unroll
      for (int nt = 0; nt < 4; ++nt)
        acc[mt][nt] = __builtin_amdgcn_mfma_f32_16x16x32_bf16(fa[mt], fb[nt], acc[mt][nt], 0, 0, 0);
    if (k + 1 < nk) {
      lstore((k + 1) & 1);               // regs hold k+1's data
      if (k + 2 < nk) gload((k + 2) * 32);
      __syncthreads();
    }
  }

  #pragma unroll
  for (int mt = 0; mt < 4; ++mt)
    #pragma unroll
    for (int nt = 0; nt < 4; ++nt) {
      int col = bn + wn + nt * 16 + lm;
      if (col >= N) continue;
      float bz = bias[col];
      #pragma unroll
      for (int i = 0; i < 4; ++i) {
        int row = bm + wm + mt * 16 + kq * 4 + i;
        float v = acc[mt][nt][i] + bz;
        if (mode == 0) {
          Cf[(size_t)row * N + col] = v;
        } else if (mode == 1) {
          if (col < 16) v = sp(v);           // softplus(delta) once here
          Cb[(size_t)row * N + col] = (__bf16)v;
        } else {
          if (col < 512) Cb[(size_t)row * 512 + col] = (__bf16)v;
          else           Cg[(size_t)row * 512 + col - 512] = (__bf16)silu(v);
        }
      }
    }
}

// ---------------- depthwise causal conv (k=4) + SiLU, bf16 in/out, 8 ch/thread
__global__ void conv_silu(const __bf16* __restrict__ xs,
                          const float* __restrict__ cw,
                          const float* __restrict__ cb,
                          __bf16* __restrict__ xc, int total) {
  int idx = blockIdx.x * 256 + threadIdx.x;   // < R*64
  if (idx >= total) return;
  int d8 = (idx & 63) * 8;
  int bt = idx >> 6;
  int t = bt % SEQC;
  const __bf16* base = xs + (size_t)(bt - t) * 512 + d8;
  float wv[8][4];
  #pragma unroll
  for (int e = 0; e < 8; ++e) {
    float4 wq = *(const float4*)&cw[(d8 + e) * 4];
    wv[e][0] = wq.x; wv[e][1] = wq.y; wv[e][2] = wq.z; wv[e][3] = wq.w;
  }
  float4 b0 = *(const float4*)&cb[d8];
  float4 b1 = *(const float4*)&cb[d8 + 4];
  float acc[8] = {b0.x, b0.y, b0.z, b0.w, b1.x, b1.y, b1.z, b1.w};
  #pragma unroll
  for (int j = 0; j < 4; ++j) {
    int ts = t - 3 + j;
    if (ts >= 0) {
      bf16x8 v = *(const bf16x8*)&base[(size_t)ts * 512];
      #pragma unroll
      for (int e = 0; e < 8; ++e) acc[e] = fmaf(wv[e][j], (float)v[e], acc[e]);
    }
  }
  bf16x8 o;
  #pragma unroll
  for (int e = 0; e < 8; ++e) o[e] = (__bf16)silu(acc[e]);
  *(bf16x8*)&xc[(size_t)bt * 512 + d8] = o;
}

// ---------------- scan phase 1: per-chunk local scan (h=0) -> hend, P (bf16)
// 256 threads = 4 d-groups; (delta|B) tile staged once for all 4 groups.
__global__ __launch_bounds__(256, 4) void scan_phase1(
    const __bf16* __restrict__ ssm, const float* __restrict__ A_log,
    const __bf16* __restrict__ xc,
    __bf16* __restrict__ hend, __bf16* __restrict__ Pp) {
  __shared__ float sb[SUB * 32];
  __shared__ __bf16 xsb[SUB * 256];
  int b = blockIdx.x, half = blockIdx.y, c = blockIdx.z;
  int tid = threadIdx.x;
  int dg0 = half * 256;
  int d = dg0 + tid;
  float a2[16];
  #pragma unroll
  for (int n = 0; n < 16; ++n) a2[n] = -__expf(A_log[d * 16 + n]) * LOG2E;
  float h[16] = {}, S[16] = {};
  size_t rowbase = (size_t)b * SEQC + c * CT;

  for (int sub = 0; sub < 2; ++sub) {
    int ts0 = sub * SUB;
    __syncthreads();
    for (int i = tid; i < SUB * 8; i += 256) {
      int tt = i >> 3, n4 = (i & 7) * 4;
      bf16x4 v = *(const bf16x4*)&ssm[(rowbase + ts0 + tt) * 32 + n4];
      float4 f = {(float)v[0], (float)v[1], (float)v[2], (float)v[3]};
      *(float4*)&sb[tt * 32 + n4] = f;
    }
    for (int i = tid; i < SUB * 64; i += 256) {
      int tt = i >> 6, j4 = (i & 63) * 4;
      *(bf16x4*)&xsb[tt * 256 + j4] =
          *(const bf16x4*)&xc[(rowbase + ts0 + tt) * 512 + dg0 + j4];
    }
    __syncthreads();
    for (int tt = 0; tt < SUB; ++tt) {
      const float4* dv = (const float4*)&sb[tt * 32];
      float4 d0 = dv[0], d1 = dv[1], d2 = dv[2], d3 = dv[3];
      float4 e0 = dv[4], e1 = dv[5], e2 = dv[6], e3 = dv[7];
      float del[16] = {d0.x, d0.y, d0.z, d0.w, d1.x, d1.y, d1.z, d1.w,
                       d2.x, d2.y, d2.z, d2.w, d3.x, d3.y, d3.z, d3.w};
      float Bv[16]  = {e0.x, e0.y, e0.z, e0.w, e1.x, e1.y, e1.z, e1.w,
                       e2.x, e2.y, e2.z, e2.w, e3.x, e3.y, e3.z, e3.w};
      float xv = (float)xsb[tt * 256 + tid];
      #pragma unroll
      for (int n = 0; n < 16; ++n) {
        S[n] += del[n];
        float e = EXP2F(a2[n] * del[n]);
        h[n] = fmaf(h[n], e, xv * Bv[n]);
      }
    }
  }
  size_t base = ((size_t)(b * NCH + c) * 512 + d) * 16;
  bf16x8 h0, h1, p0, p1;
  #pragma unroll
  for (int n = 0; n < 8; ++n) {
    h0[n] = (__bf16)h[n]; h1[n] = (__bf16)h[n + 8];
    p0[n] = (__bf16)EXP2F(a2[n] * S[n]);
    p1[n] = (__bf16)EXP2F(a2[n + 8] * S[n + 8]);
  }
  *(bf16x8*)&hend[base] = h0; *(bf16x8*)&hend[base + 8] = h1;
  *(bf16x8*)&Pp[base] = p0;   *(bf16x8*)&Pp[base + 8] = p1;
}

// ---------------- scan phase 2: sequential carry composition (hend -> hin in place)
__global__ __launch_bounds__(64) void scan_combine(
    __bf16* __restrict__ hend, const __bf16* __restrict__ Pp) {
  int b = blockIdx.x;
  int d = blockIdx.y * 64 + threadIdx.x;
  float hp[16] = {};
  for (int c = 0; c < NCH; ++c) {
    size_t base = ((size_t)(b * NCH + c) * 512 + d) * 16;
    bf16x8 he0 = *(const bf16x8*)&hend[base];
    bf16x8 he1 = *(const bf16x8*)&hend[base + 8];
    bf16x8 pp0 = *(const bf16x8*)&Pp[base];
    bf16x8 pp1 = *(const bf16x8*)&Pp[base + 8];
    bf16x8 o0, o1;
    #pragma unroll
    for (int n = 0; n < 8; ++n) {
      o0[n] = (__bf16)hp[n]; o1[n] = (__bf16)hp[n + 8];
      hp[n]     = fmaf((float)pp0[n], hp[n],     (float)he0[n]);
      hp[n + 8] = fmaf((float)pp1[n], hp[n + 8], (float)he1[n]);
    }
    *(bf16x8*)&hend[base] = o0; *(bf16x8*)&hend[base + 8] = o1;
  }
}

// ---------------- scan phase 3: local scan with carry, y, gate -> yc bf16
// 256 threads = 4 d-groups sharing the (delta|B) stage.
__global__ __launch_bounds__(256, 4) void scan_phase3(
    const __bf16* __restrict__ ssm, const float* __restrict__ A_log,
    const float* __restrict__ Dp, const __bf16* __restrict__ xc,
    const __bf16* __restrict__ gate, const __bf16* __restrict__ hin,
    __bf16* __restrict__ yc) {
  __shared__ float sb[SUB * 32];
  __shared__ __bf16 xsb[SUB * 256];
  int b = blockIdx.x, half = blockIdx.y, c = blockIdx.z;
  int tid = threadIdx.x;
  int dg0 = half * 256;
  int d = dg0 + tid;
  float a2[16];
  #pragma unroll
  for (int n = 0; n < 16; ++n) a2[n] = -__expf(A_log[d * 16 + n]) * LOG2E;
  float Dv = Dp[d];
  float h[16];
  {
    size_t base = ((size_t)(b * NCH + c) * 512 + d) * 16;
    bf16x8 h0 = *(const bf16x8*)&hin[base];
    bf16x8 h1 = *(const bf16x8*)&hin[base + 8];
    #pragma unroll
    for (int n = 0; n < 8; ++n) { h[n] = (float)h0[n]; h[n + 8] = (float)h1[n]; }
  }
  size_t rowbase = (size_t)b * SEQC + c * CT;

  for (int sub = 0; sub < 2; ++sub) {
    int ts0 = sub * SUB;
    __syncthreads();
    for (int i = tid; i < SUB * 8; i += 256) {
      int tt = i >> 3, n4 = (i & 7) * 4;
      bf16x4 v = *(const bf16x4*)&ssm[(rowbase + ts0 + tt) * 32 + n4];
      float4 f = {(float)v[0], (float)v[1], (float)v[2], (float)v[3]};
      *(float4*)&sb[tt * 32 + n4] = f;
    }
    for (int i = tid; i < SUB * 64; i += 256) {
      int tt = i >> 6, j4 = (i & 63) * 4;
      *(bf16x4*)&xsb[tt * 256 + j4] =
          *(const bf16x4*)&xc[(rowbase + ts0 + tt) * 512 + dg0 + j4];
    }
    __syncthreads();
    for (int tt = 0; tt < SUB; ++tt) {
      const float4* dv = (const float4*)&sb[tt * 32];
      float4 d0 = dv[0], d1 = dv[1], d2 = dv[2], d3 = dv[3];
      float4 e0 = dv[4], e1 = dv[5], e2 = dv[6], e3 = dv[7];
      float del[16] = {d0.x, d0.y, d0.z, d0.w, d1.x, d1.y, d1.z, d1.w,
                       d2.x, d2.y, d2.z, d2.w, d3.x, d3.y, d3.z, d3.w};
      float Bv[16]  = {e0.x, e0.y, e0.z, e0.w, e1.x, e1.y, e1.z, e1.w,
                       e2.x, e2.y, e2.z, e2.w, e3.x, e3.y, e3.z, e3.w};
      float xv = (float)xsb[tt * 256 + tid];
      float y0 = 0.f, y1 = 0.f, y2 = 0.f, y3 = 0.f;
      #pragma unroll
      for (int n = 0; n < 4; ++n) {
        float e = EXP2F(a2[n] * del[n]);
        h[n] = fmaf(h[n], e, xv * Bv[n]);
        y0 = fmaf(h[n], Bv[n], y0);
      }
      #pragma unroll
      for (int n = 4; n < 8; ++n) {
        float e = EXP2F(a2[n] * del[n]);
        h[n] = fmaf(h[n], e, xv * Bv[n]);
        y1 = fmaf(h[n], Bv[n], y1);
      }
      #pragma unroll
      for (int n = 8; n < 12; ++n) {
        float e = EXP2F(a2[n] * del[n]);
        h[n] = fmaf(h[n], e, xv * Bv[n]);
        y2 = fmaf(h[n], Bv[n], y2);
      }
      #pragma unroll
      for (int n = 12; n < 16; ++n) {
        float e = EXP2F(a2[n] * del[n]);
        h[n] = fmaf(h[n], e, xv * Bv[n]);
        y3 = fmaf(h[n], Bv[n], y3);
      }
      xsb[tt * 256 + tid] = (__bf16)fmaf(Dv, xv, (y0 + y1) + (y2 + y3));
    }
    __syncthreads();
    for (int i = tid; i < SUB * 64; i += 256) {
      int tt = i >> 6, j4 = (i & 63) * 4;
      size_t o = (rowbase + ts0 + tt) * 512 + dg0 + j4;
      bf16x4 y4 = *(const bf16x4*)&xsb[tt * 256 + j4];
      bf16x4 g4 = *(const bf16x4*)&gate[o];
      bf16x4 r;
      #pragma unroll
      for (int e = 0; e < 4; ++e) r[e] = (__bf16)((float)y4[e] * (float)g4[e]);
      *(bf16x4*)&yc[o] = r;
    }
  }
}

// ---------------- x = LayerNorm(reconstruct(xh,xl) + ob), re-split; 4 rows/block
__global__ __launch_bounds__(256) void add_ln(
    __bf16* __restrict__ xh, __bf16* __restrict__ xl,
    const float* __restrict__ ob,
    const float* __restrict__ g, const float* __restrict__ bb) {
  int lane = threadIdx.x & 63;
  size_t base = ((size_t)blockIdx.x * 4 + (threadIdx.x >> 6)) * 256;
  bf16x4 h4 = *(const bf16x4*)&xh[base + lane * 4];
  bf16x4 l4 = *(const bf16x4*)&xl[base + lane * 4];
  float4 o4 = *(const float4*)&ob[base + lane * 4];
  float ov[4] = {o4.x, o4.y, o4.z, o4.w};
  float v[4];
  #pragma unroll
  for (int i = 0; i < 4; ++i) v[i] = (float)h4[i] + (float)l4[i] + ov[i];
  float s = v[0] + v[1] + v[2] + v[3];
  #pragma unroll
  for (int off = 32; off > 0; off >>= 1) s += __shfl_down(s, off);
  float mu = __shfl(s, 0) * (1.f / 256.f);
  float var = 0.f;
  #pragma unroll
  for (int i = 0; i < 4; ++i) { float dd = v[i] - mu; var = fmaf(dd, dd, var); }
  #pragma unroll
  for (int off = 32; off > 0; off >>= 1) var += __shfl_down(var, off);
  float r = rsqrtf(__shfl(var, 0) * (1.f / 256.f) + LN_EPSF);
  float4 gv = *(const float4*)&g[lane * 4];
  float4 bv = *(const float4*)&bb[lane * 4];
  float gg[4] = {gv.x, gv.y, gv.z, gv.w};
  float bbv[4] = {bv.x, bv.y, bv.z, bv.w};
  bf16x4 hq, lq;
  #pragma unroll
  for (int i = 0; i < 4; ++i) {
    float o = (v[i] - mu) * r * gg[i] + bbv[i];
    __bf16 hh = (__bf16)o;
    hq[i] = hh;
    lq[i] = (__bf16)(o - (float)hh);
  }
  *(bf16x4*)&xh[base + lane * 4] = hq;
  *(bf16x4*)&xl[base + lane * 4] = lq;
}

// ---------------- fin[b][256] = reconstruct(x) at t=899
__global__ void extract_final(const __bf16* __restrict__ xh,
                              const __bf16* __restrict__ xl,
                              float* __restrict__ fin) {
  int b = blockIdx.x;
  int c = threadIdx.x;
  size_t o = ((size_t)b * SEQC + (SEQC - 1)) * D_MODELC + c;
  fin[(size_t)b * 256 + c] = (float)xh[o] + (float)xl[o];
}

// ---------------- final heads
__global__ __launch_bounds__(128) void heads_kernel(
    const float* __restrict__ fin,
    const float* __restrict__ cnt1_w, const float* __restrict__ cnt1_b,
    const float* __restrict__ cnt2_w, const float* __restrict__ cnt2_b,
    const float* __restrict__ col1_w, const float* __restrict__ col1_b,
    const float* __restrict__ col2_w, const float* __restrict__ col2_b,
    float* __restrict__ out) {
  int b = blockIdx.x;
  int tid = threadIdx.x;
  __shared__ float f[256];
  __shared__ float hc[128];
  __shared__ float hl[128];
  f[tid] = fin[b * 256 + tid];
  f[tid + 128] = fin[b * 256 + tid + 128];
  __syncthreads();
  float s1 = cnt1_b[tid], s2 = col1_b[tid];
  for (int c = 0; c < 256; ++c) {
    float v = f[c];
    s1 = fmaf(v, cnt1_w[c * 128 + tid], s1);
    s2 = fmaf(v, col1_w[c * 128 + tid], s2);
  }
  hc[tid] = fmaxf(s1, 0.f);
  hl[tid] = fmaxf(s2, 0.f);
  __syncthreads();
  if (tid == 0) {
    float t = cnt2_b[0];
    for (int j = 0; j < 128; ++j) t = fmaf(hc[j], cnt2_w[j], t);
    out[b] = fmaxf(t, 0.f);
  }
  if (tid < 10) {
    float t = col2_b[tid];
    for (int j = 0; j < 128; ++j) t = fmaf(hl[j], col2_w[j * 10 + tid], t);
    out[64 + b * 10 + tid] = fmaxf(t, 0.f);
  }
}

extern "C" void kernel_launch(void* const* d_in, const int* in_sizes, int n_in,
                              void* d_out, int out_size, void* d_ws, size_t ws_size,
                              hipStream_t stream) {
  const int*   grid   = (const int*)d_in[0];
  const float* cemb   = (const float*)d_in[1];
  const float* pemb   = (const float*)d_in[2];
  const float* in_w   = (const float*)d_in[3];
  const float* in_b   = (const float*)d_in[4];
  const float* conv_w = (const float*)d_in[5];
  const float* conv_b = (const float*)d_in[6];
  const float* xproj_w= (const float*)d_in[7];
  const float* xproj_b= (const float*)d_in[8];
  const float* A_log  = (const float*)d_in[9];
  const float* Dp     = (const float*)d_in[10];
  const float* out_w  = (const float*)d_in[11];
  const float* out_b  = (const float*)d_in[12];
  const float* ln_g   = (const float*)d_in[13];
  const float* ln_b   = (const float*)d_in[14];
  const float* cnt1_w = (const float*)d_in[15];
  const float* cnt1_b = (const float*)d_in[16];
  const float* cnt2_w = (const float*)d_in[17];
  const float* cnt2_b = (const float*)d_in[18];
  const float* col1_w = (const float*)d_in[19];
  const float* col1_b = (const float*)d_in[20];
  const float* col2_w = (const float*)d_in[21];
  const float* col2_b = (const float*)d_in[22];

  const int R = BATCHC * SEQC;  // 57600
  float* ws = (float*)d_ws;
  size_t off = 0;
  auto alloc = [&](size_t fl) { float* p = ws + off; off += (fl + 63) & ~(size_t)63; return p; };

  float*  fin   = alloc((size_t)BATCHC * 256);
  __bf16* wi    = (__bf16*)alloc((size_t)N_LAYERSC * 1024 * 256 / 2);
  __bf16* wx    = (__bf16*)alloc((size_t)N_LAYERSC * 32 * 512 / 2);
  __bf16* wo    = (__bf16*)alloc((size_t)N_LAYERSC * 256 * 512 / 2);
  __bf16* xh    = (__bf16*)alloc((size_t)R * 256 / 2);
  __bf16* xl    = (__bf16*)alloc((size_t)R * 256 / 2);
  __bf16* xsyc  = (__bf16*)alloc((size_t)R * 512 / 2);   // xs then yc
  float*  gateob= alloc((size_t)R * 512 / 2);            // gate bf16, then ob fp32
  __bf16* xc    = (__bf16*)alloc((size_t)R * 512 / 2);
  __bf16* ssm   = (__bf16*)alloc((size_t)R * 32 / 2);
  __bf16* hend  = (__bf16*)alloc((size_t)BATCHC * NCH * 512 * 16 / 2);
  __bf16* Pp    = (__bf16*)alloc((size_t)BATCHC * NCH * 512 * 16 / 2);
  __bf16* gate  = (__bf16*)gateob;
  float*  ob    = gateob;

  // weight prep (once per call)
  wprep<<<dim3(1024, N_LAYERSC), 256, 0, stream>>>(in_w, wi, 256, 1024, 8);
  wprep<<<dim3(64, N_LAYERSC), 256, 0, stream>>>(xproj_w, wx, 512, 32, 9);
  wprep<<<dim3(512, N_LAYERSC), 256, 0, stream>>>(out_w, wo, 512, 256, 9);

  embed_kernel<<<R, 256, 0, stream>>>(grid, cemb, pemb, xh, xl);

  for (int l = 0; l < N_LAYERSC; ++l) {
    // in-proj: xs (bf16) + gate = silu(res) (bf16). grid: x=col tiles (8)
    gemm_bf16<<<dim3(8, R / 128), 256, 0, stream>>>(
        xh, wi + (size_t)l * 1024 * 256, in_b + l * 1024,
        nullptr, xsyc, gate, R, 1024, 256, 2);
    conv_silu<<<(R * 64 + 255) / 256, 256, 0, stream>>>(
        xsyc, conv_w + (size_t)l * 512 * 4, conv_b + l * 512, xc, R * 64);
    // x-proj: ssm bf16, softplus fused on delta cols
    gemm_bf16<<<dim3(1, R / 128), 256, 0, stream>>>(
        xc, wx + (size_t)l * 32 * 512, xproj_b + l * 32,
        nullptr, ssm, nullptr, R, 32, 512, 1);
    scan_phase1<<<dim3(BATCHC, 2, NCH), 256, 0, stream>>>(
        ssm, A_log + (size_t)l * 512 * 16, xc, hend, Pp);
    scan_combine<<<dim3(BATCHC, 8), 64, 0, stream>>>(hend, Pp);
    scan_phase3<<<dim3(BATCHC, 2, NCH), 256, 0, stream>>>(
        ssm, A_log + (size_t)l * 512 * 16, Dp + l * 512, xc, gate, hend, xsyc);
    // out-proj: ob fp32. grid: x=col tiles (2)
    gemm_bf16<<<dim3(2, R / 128), 256, 0, stream>>>(
        xsyc, wo + (size_t)l * 256 * 512, out_b + l * 256,
        ob, nullptr, nullptr, R, 256, 512, 0);
    add_ln<<<R / 4, 256, 0, stream>>>(xh, xl, ob, ln_g, ln_b);
  }

  extract_final<<<BATCHC, 256, 0, stream>>>(xh, xl, fin);
  heads_kernel<<<BATCHC, 128, 0, stream>>>(
      fin, cnt1_w, cnt1_b, cnt2_w, cnt2_b, col1_w, col1_b, col2_w, col2_b,
      (float*)d_out);
}